// Round 8
// baseline (3223.035 us; speedup 1.0000x reference)
//
#include <hip/hip_runtime.h>

#define DEV __device__ __forceinline__

using bf16x8 = __attribute__((ext_vector_type(8))) __bf16;
using f32x4  = __attribute__((ext_vector_type(4))) float;
using u16x8  = __attribute__((ext_vector_type(8))) unsigned short;
using u16x4  = __attribute__((ext_vector_type(4))) unsigned short;

DEV unsigned short f2bf(float f) {
  unsigned u = __builtin_bit_cast(unsigned, f);
  u += 0x7fffu + ((u >> 16) & 1u);
  return (unsigned short)(u >> 16);
}
DEV float bf2f(unsigned short h) {
  unsigned u = ((unsigned)h) << 16;
  return __builtin_bit_cast(float, u);
}
DEV f32x4 mfma16(u16x8 a, u16x8 b, f32x4 c) {
  return __builtin_amdgcn_mfma_f32_16x16x32_bf16(
      __builtin_bit_cast(bf16x8, a), __builtin_bit_cast(bf16x8, b), c, 0, 0, 0);
}
DEV f32x4 zero4() { f32x4 z = {0.f, 0.f, 0.f, 0.f}; return z; }

// async global->LDS, 16B per lane. lds dest = wave-uniform base + lane*16;
// global src is per-lane.
DEV void glds16(const unsigned short* g, unsigned short* l) {
  __builtin_amdgcn_global_load_lds(
      (const __attribute__((address_space(1))) unsigned int*)g,
      (__attribute__((address_space(3))) unsigned int*)l, 16, 0, 0);
}

#define PH_BAR()                          \
  do {                                    \
    __builtin_amdgcn_sched_barrier(0);    \
    __builtin_amdgcn_s_barrier();         \
    __builtin_amdgcn_sched_barrier(0);    \
  } while (0)

enum { EPI_BIAS = 0, EPI_RELU = 1, EPI_OUT = 2, EPI_QKV = 3 };

// ---------------------------------------------------------------------------
// 256x256 bf16 MFMA GEMM, BK=32 double-buffered (64 KB LDS -> 2 blocks/CU)
// with fine phase interleave + counted vmcnt (round-6 schedule, FIXED swizzle).
// Swizzle (verified 0-conflict, rounds 2-3): 16B chunk c of row r at slot
// c ^ ((r&15)>>1 & 3); read offset (q ^ ((ln>>1)&3)); staging source chunk
// (lane&3) ^ ((lane>>3)&3) with row-in-16 = lane>>2 -- same involution.
// 512 thr = 8 waves (2M x 4N), per-wave out 128x64, acc[8][4]. Per tile u:
//   ph0: ds_read A0-3 + B0-3 (8);              BAR; 16 MFMA; BAR
//   ph1: ds_read A4-7 (4); stage B(u+2)->buf;  BAR; 16 MFMA; BAR
//   boundary: stage A(u+2)->buf; vmcnt(4|0 tail); BAR
// Ledger: tile u staged during iter u-2; boundary vmcnt(4) drains tile u+1,
// leaves u+2's 4 loads IN FLIGHT across the barrier. WAR: stages issue only
// after the barrier that closes all reads of the target region.
// EPI_QKV: n0>=1024 tiles (V block) written TRANSPOSED into Cv (vt layout);
// 4 consecutive rows = 4 keys = one 8B store. Bit-identical values.
// Requires M%256==0, N%256==0, K%32==0, Mt%8==0.
// ---------------------------------------------------------------------------
template <int EPI>
__global__ __launch_bounds__(512, 2) void gemm32_k(
    const unsigned short* __restrict__ A, const unsigned short* __restrict__ Bt,
    const float* __restrict__ bias, unsigned short* __restrict__ C,
    unsigned short* __restrict__ Cv, int N, int K) {
  __shared__ unsigned short As[2][8192];  // [buf][256 rows x 32 shorts]
  __shared__ unsigned short Bs[2][8192];
  const int tid = threadIdx.x;
  const int lane = tid & 63, wv = tid >> 6;  // 8 waves
  const int q = lane >> 4, ln = lane & 15;
  const int wr = wv >> 2, wc = wv & 3;       // wave grid 2M x 4N
  const int sw = ((q ^ ((ln >> 1) & 3)) << 3);  // verified 0-conflict (r3)

  const int Nt = gridDim.x, Mt = gridDim.y;
  const int lin = blockIdx.x + Nt * blockIdx.y;
  const int xcd = lin & 7;
  const int j = lin >> 3;
  const int mi = xcd * (Mt >> 3) + j / Nt;
  const int ni = j % Nt;
  const int m0 = mi << 8, n0 = ni << 8;

  f32x4 acc[8][4];
#pragma unroll
  for (int i = 0; i < 8; ++i)
#pragma unroll
    for (int jj = 0; jj < 4; ++jj) acc[i][jj] = zero4();

  // staging: per glds a wave covers 16 rows x 32 cols (1 KB). lane L -> row
  // wv*16+(L>>2), dest chunk L&3; source pre-swizzled (L&3)^((L>>3)&3).
  const int sr = lane >> 2;                       // row-in-16
  const int sc = ((lane & 3) ^ ((lane >> 3) & 3)) << 3;
  const unsigned short* Abase = A + (size_t)(m0 + wv * 16 + sr) * K + sc;
  const unsigned short* Bbase = Bt + (size_t)(n0 + wv * 16 + sr) * K + sc;

  const int T = K >> 5;  // 32-wide K-tiles

  auto stA = [&](int buf, int t) {
    unsigned short* d = &As[buf][wv * 512];
    const unsigned short* s = Abase + t * 32;
    glds16(s, d);
    glds16(s + (size_t)128 * K, d + 4096);
  };
  auto stB = [&](int buf, int t) {
    unsigned short* d = &Bs[buf][wv * 512];
    const unsigned short* s = Bbase + t * 32;
    glds16(s, d);
    glds16(s + (size_t)128 * K, d + 4096);
  };

  // prologue: stage t0 then t1; vmcnt(4) -> t0 landed, t1 in flight.
  stA(0, 0);
  stB(0, 0);
  if (T > 1) {
    stA(1, 1);
    stB(1, 1);
    asm volatile("s_waitcnt vmcnt(4)" ::: "memory");
  } else {
    asm volatile("s_waitcnt vmcnt(0)" ::: "memory");
  }
  PH_BAR();

  for (int u = 0; u < T; ++u) {
    const int cur = u & 1;
    const unsigned short* Ab = &As[cur][0];
    const unsigned short* Bb = &Bs[cur][0];
    u16x8 a0[4], a1[4], b0[4];

    // ---- ph0: A0-3 (4) + B0-3 (4)
#pragma unroll
    for (int mt = 0; mt < 4; ++mt)
      a0[mt] = *(const u16x8*)(Ab + (wr * 128 + mt * 16 + ln) * 32 + sw);
#pragma unroll
    for (int nt = 0; nt < 4; ++nt)
      b0[nt] = *(const u16x8*)(Bb + (wc * 64 + nt * 16 + ln) * 32 + sw);
    PH_BAR();
    __builtin_amdgcn_s_setprio(1);
#pragma unroll
    for (int nt = 0; nt < 4; ++nt)
#pragma unroll
      for (int mt = 0; mt < 4; ++mt) acc[mt][nt] = mfma16(a0[mt], b0[nt], acc[mt][nt]);
    __builtin_amdgcn_s_setprio(0);
    PH_BAR();

    // ---- ph1: A4-7 (4); stage B(u+2) (B-reads of u closed by ph0 barriers)
#pragma unroll
    for (int mt = 0; mt < 4; ++mt)
      a1[mt] = *(const u16x8*)(Ab + (wr * 128 + (mt + 4) * 16 + ln) * 32 + sw);
    if (u + 2 < T) stB(cur, u + 2);
    PH_BAR();
    __builtin_amdgcn_s_setprio(1);
#pragma unroll
    for (int nt = 0; nt < 4; ++nt)
#pragma unroll
      for (int mt = 0; mt < 4; ++mt)
        acc[mt + 4][nt] = mfma16(a1[mt], b0[nt], acc[mt + 4][nt]);
    __builtin_amdgcn_s_setprio(0);
    PH_BAR();

    // ---- boundary: stage A(u+2) (A-reads of u closed); counted vmcnt
    if (u + 1 < T) {
      if (u + 2 < T) {
        stA(cur, u + 2);
        asm volatile("s_waitcnt vmcnt(4)" ::: "memory");
      } else {
        asm volatile("s_waitcnt vmcnt(0)" ::: "memory");
      }
      PH_BAR();
    }
  }

#pragma unroll
  for (int mt = 0; mt < 8; ++mt) {
    const int rowb = m0 + wr * 128 + mt * 16 + q * 4;
    const int seq = rowb >> 9, key0 = rowb & 511;
#pragma unroll
    for (int nt = 0; nt < 4; ++nt) {
      const int col = n0 + wc * 64 + nt * 16 + ln;
      const float bs = bias[col];
      if (EPI == EPI_QKV && n0 >= 1024) {
        // V block: write transposed into vt [(seq*8+h)*64+hd][512 keys]
        const int hh = (col - 1024) >> 6, hd = col & 63;
        u16x4 pk;
#pragma unroll
        for (int r = 0; r < 4; ++r) pk[r] = f2bf(acc[mt][nt][r] + bs);
        *(u16x4*)(Cv + ((size_t)((seq * 8 + hh) * 64 + hd)) * 512 + key0) = pk;
      } else {
#pragma unroll
        for (int r = 0; r < 4; ++r) {
          float v = acc[mt][nt][r] + bs;
          if (EPI == EPI_RELU) v = fmaxf(v, 0.f);
          C[(size_t)(rowb + r) * N + col] = f2bf(v);
        }
      }
    }
  }
}

// ---------------------------------------------------------------------------
// old 128x128 GEMM kept for out-proj (N=128 doesn't fit a 256 tile)
// ---------------------------------------------------------------------------
template <int EPI>
__global__ __launch_bounds__(256) void gemm_k(
    const unsigned short* __restrict__ A, const unsigned short* __restrict__ Bt,
    const float* __restrict__ bias, unsigned short* __restrict__ C, int N, int K) {
  __shared__ unsigned short As[128 * 64];  // 16 KB, swizzled chunks
  __shared__ unsigned short Bs[128 * 64];
  const int tid = threadIdx.x;
  const int lane = tid & 63, wv = tid >> 6;
  const int q = lane >> 4, ln = lane & 15;
  const int wr = wv >> 1, wc = wv & 1;

  const int Nt = gridDim.x, Mt = gridDim.y;
  const int lin = blockIdx.x + Nt * blockIdx.y;
  const int xcd = lin & 7;
  const int j = lin >> 3;
  const int mi = xcd * (Mt >> 3) + j / Nt;
  const int ni = j % Nt;
  const int m0 = mi << 7, n0 = ni << 7;

  f32x4 acc[4][4];
#pragma unroll
  for (int i = 0; i < 4; ++i)
#pragma unroll
    for (int jj = 0; jj < 4; ++jj) acc[i][jj] = zero4();

  const int ra = lane >> 3;              // row within 8-row group
  const int ca = ((lane & 7) ^ ra) << 3; // swizzled source col-chunk (shorts)
  const unsigned short* Ap = A + (size_t)(m0 + wv * 32 + ra) * K + ca;
  const unsigned short* Bp = Bt + (size_t)(n0 + wv * 32 + ra) * K + ca;
  unsigned short* AsW = As + wv * 2048;  // 4 issues x 512 shorts
  unsigned short* BsW = Bs + wv * 2048;
  const int ln7 = ln & 7;

  for (int kb = 0; kb < K; kb += 64) {
    __syncthreads();  // WAR: prior ds_reads done before overwrite
#pragma unroll
    for (int t = 0; t < 4; ++t) {
      glds16(Ap + (size_t)(t * 8) * K + kb, AsW + t * 512);
      glds16(Bp + (size_t)(t * 8) * K + kb, BsW + t * 512);
    }
    __syncthreads();  // barrier drains vmcnt -> tiles visible
#pragma unroll
    for (int kk = 0; kk < 2; ++kk) {
      const int c = kk * 4 + q;
      const int lo = ln * 64 + ((c ^ ln7) << 3);  // lane offset (shorts)
      u16x8 af[4];
#pragma unroll
      for (int mt = 0; mt < 4; ++mt)
        af[mt] = *(const u16x8*)(As + (wr * 64 + mt * 16) * 64 + lo);
#pragma unroll
      for (int nt = 0; nt < 4; ++nt) {
        u16x8 bf = *(const u16x8*)(Bs + (wc * 64 + nt * 16) * 64 + lo);
#pragma unroll
        for (int mt = 0; mt < 4; ++mt) acc[mt][nt] = mfma16(af[mt], bf, acc[mt][nt]);
      }
    }
  }

#pragma unroll
  for (int mt = 0; mt < 4; ++mt) {
    const int rowb = m0 + wr * 64 + mt * 16 + q * 4;
#pragma unroll
    for (int nt = 0; nt < 4; ++nt) {
      const int col = n0 + wc * 64 + nt * 16 + ln;
      if (EPI == EPI_OUT && col >= 32) continue;
      const float bs = bias[col];
      const int ldc = (EPI == EPI_OUT) ? 32 : N;
#pragma unroll
      for (int r = 0; r < 4; ++r) {
        float v = acc[mt][nt][r] + bs;
        if (EPI == EPI_RELU) v = fmaxf(v, 0.f);
        C[(size_t)(rowb + r) * ldc + col] = f2bf(v);
      }
    }
  }
}

// ---------------------------------------------------------------------------
// Flash attention with alibi, NO max-subtraction (scores bounded; exp2 direct).
// Swapped QK^T; b64 P-stores; K/V DOUBLE-BUFFERED with counted vmcnt so the
// next tile's fetch hides under this tile's compute. Ps aliases Qs. 50 KB LDS.
// ---------------------------------------------------------------------------
__global__ __launch_bounds__(256) void attn_k(const unsigned short* __restrict__ qkv,
                                              const unsigned short* __restrict__ vt,
                                              unsigned short* __restrict__ o) {
  __shared__ unsigned short Qs[128 * 72];    // Q tile; reused as Ps after prologue
  __shared__ unsigned short Ks[2][64 * 64];  // XOR-chunk swizzled, glds16-staged
  __shared__ unsigned short Vts[2][64 * 64]; // [hd][key-chunk swizzled]
  unsigned short* Ps = Qs;
  const int tid = threadIdx.x;
  const int lane = tid & 63, w = tid >> 6, q = lane >> 4, ln = lane & 15;
  const int bh = blockIdx.x;
  const int seq = bh >> 3, h = bh & 7;
  const int qt = blockIdx.y;
  const size_t tokb = (size_t)seq * 512;
  const int qoff = h * 64, koff = 512 + h * 64;
  const float c1 = 0.125f * 1.44269504f;                   // scale * log2e
  const float c2 = ((h < 4) ? 1.0f : 0.5f) * 1.44269504f;  // slope * log2e

#pragma unroll
  for (int p = 0; p < 4; ++p) {  // stage Q 128x64 (stride 72)
    int c = p * 256 + tid;
    int row = c >> 3, cc = (c & 7) << 3;
    u16x8 v = *(const u16x8*)(qkv + (tokb + qt * 128 + row) * 1536 + qoff + cc);
    *(u16x8*)(Qs + row * 72 + cc) = v;
  }

  const int sr = lane >> 3;                // row-in-8
  const int sc = ((lane & 7) ^ sr) << 3;   // swizzled chunk (shorts)
  const unsigned short* Kp = qkv + (tokb + w * 16 + sr) * 1536 + koff + sc;
  const unsigned short* Vp = vt + ((size_t)bh * 64 + w * 16 + sr) * 512 + sc;
  const int ln7 = ln & 7;

  auto stage = [&](int kt, int buf) {
    unsigned short* KsW = &Ks[buf][w * 1024];
    unsigned short* VsW = &Vts[buf][w * 1024];
    glds16(Kp + (size_t)(kt * 64) * 1536, KsW);
    glds16(Kp + (size_t)(kt * 64 + 8) * 1536, KsW + 512);
    glds16(Vp + kt * 64, VsW);
    glds16(Vp + kt * 64 + (size_t)8 * 512, VsW + 512);
  };

  stage(0, 0);  // prologue: kt0 in flight during Q-read setup

  __syncthreads();  // Q visible
  u16x8 aq[2][2];
#pragma unroll
  for (int mt = 0; mt < 2; ++mt)
#pragma unroll
    for (int kc = 0; kc < 2; ++kc)
      aq[mt][kc] = *(const u16x8*)(Qs + (w * 32 + mt * 16 + ln) * 72 + kc * 32 + q * 8);

  float lacc[2] = {0.f, 0.f};
  f32x4 o_acc[2][4];
#pragma unroll
  for (int mt = 0; mt < 2; ++mt)
#pragma unroll
    for (int ht = 0; ht < 4; ++ht) o_acc[mt][ht] = zero4();

  for (int kt = 0; kt < 8; ++kt) {
    const int buf = kt & 1;
    __syncthreads();  // all waves done with buf^1 (and Ps writes of kt-1 settled)
    if (kt + 1 < 8) {
      stage(kt + 1, buf ^ 1);
      asm volatile("s_waitcnt vmcnt(4)" ::: "memory");  // drain kt; kt+1 in flight
    } else {
      asm volatile("s_waitcnt vmcnt(0)" ::: "memory");
    }
    __builtin_amdgcn_sched_barrier(0);
    __builtin_amdgcn_s_barrier();  // kt's K/V visible to all waves
    __builtin_amdgcn_sched_barrier(0);

    // QK^T, SWAPPED operands: lane (q,ln) gets S[qrow=w*32+mt*16+ln][k=nt*16+q*4+r]
    f32x4 sacc[2][4];
#pragma unroll
    for (int mt = 0; mt < 2; ++mt)
#pragma unroll
      for (int nt = 0; nt < 4; ++nt) sacc[mt][nt] = zero4();
#pragma unroll
    for (int nt = 0; nt < 4; ++nt)
#pragma unroll
      for (int kc = 0; kc < 2; ++kc) {
        u16x8 bk = *(const u16x8*)(&Ks[buf][(nt * 16 + ln) * 64 + (((kc * 4 + q) ^ ln7) << 3)]);
#pragma unroll
        for (int mt = 0; mt < 2; ++mt) sacc[mt][nt] = mfma16(bk, aq[mt][kc], sacc[mt][nt]);
      }

    // P = exp2(S*c1 - c2*|dq-dk|); 4 contiguous k per (mt,nt) -> b64 stores.
    const float qp0 = (float)(qt * 128 + w * 32 + ln);
    const float kb0 = (float)(kt * 64 + q * 4);
#pragma unroll
    for (int mt = 0; mt < 2; ++mt) {
      const float qpm = qp0 + (float)(mt * 16);
#pragma unroll
      for (int nt = 0; nt < 4; ++nt) {
        const float kp = kb0 + (float)(nt * 16);
        u16x4 pk;
#pragma unroll
        for (int r = 0; r < 4; ++r) {
          const float ad = fabsf(qpm - (kp + (float)r));
          const float p = exp2f(fmaf(sacc[mt][nt][r], c1, -c2 * ad));
          const unsigned u = __builtin_bit_cast(unsigned, p);
          const unsigned short pb = (unsigned short)((u + 0x8000u) >> 16);
          pk[r] = pb;
          lacc[mt] += bf2f(pb);  // sum of the *stored* values
        }
        *(u16x4*)(Ps + (w * 32 + mt * 16 + ln) * 72 + nt * 16 + q * 4) = pk;
      }
    }
    // P @ V  (Ps rows are wave-private; in-wave LDS ordering suffices)
#pragma unroll
    for (int kc = 0; kc < 2; ++kc) {
      u16x8 pa[2];
#pragma unroll
      for (int mt = 0; mt < 2; ++mt)
        pa[mt] = *(const u16x8*)(Ps + (w * 32 + mt * 16 + ln) * 72 + kc * 32 + q * 8);
#pragma unroll
      for (int ht = 0; ht < 4; ++ht) {
        u16x8 bv = *(const u16x8*)(&Vts[buf][(ht * 16 + ln) * 64 + (((kc * 4 + q) ^ ln7) << 3)]);
#pragma unroll
        for (int mt = 0; mt < 2; ++mt) o_acc[mt][ht] = mfma16(pa[mt], bv, o_acc[mt][ht]);
      }
    }
  }

  // row-sums: reduce across q-groups, redistribute to o_acc layout via shfl.
  float rl[2][4];
#pragma unroll
  for (int mt = 0; mt < 2; ++mt) {
    float l = lacc[mt];
    l += __shfl_xor(l, 16, 64);
    l += __shfl_xor(l, 32, 64);
    const int sb = (lane >> 4) * 20;
#pragma unroll
    for (int r = 0; r < 4; ++r) rl[mt][r] = 1.0f / __shfl(l, sb + r, 64);
  }

#pragma unroll
  for (int mt = 0; mt < 2; ++mt)
#pragma unroll
    for (int ht = 0; ht < 4; ++ht)
#pragma unroll
      for (int r = 0; r < 4; ++r) {
        const int row = qt * 128 + w * 32 + mt * 16 + q * 4 + r;
        const float val = o_acc[mt][ht][r] * rl[mt][r];
        o[(tokb + row) * 512 + h * 64 + ht * 16 + ln] = f2bf(val);
      }
}

// ---------------------------------------------------------------------------
// Fused residual + LayerNorm (in-place capable)
// ---------------------------------------------------------------------------
__global__ __launch_bounds__(256) void ln_k(const unsigned short* res,
                                            const unsigned short* __restrict__ y,
                                            const float* __restrict__ g,
                                            const float* __restrict__ b,
                                            unsigned short* out) {
  const int lane = threadIdx.x & 63, wv = threadIdx.x >> 6;
  const size_t row = (size_t)blockIdx.x * 4 + wv;
  const size_t base = row * 512 + lane * 8;
  u16x8 rv = *(const u16x8*)(res + base);
  u16x8 yv = *(const u16x8*)(y + base);
  float v[8];
  float s = 0.f, s2 = 0.f;
#pragma unroll
  for (int i = 0; i < 8; ++i) {
    v[i] = bf2f(rv[i]) + bf2f(yv[i]);
    s += v[i];
    s2 += v[i] * v[i];
  }
#pragma unroll
  for (int m = 1; m < 64; m <<= 1) {
    s += __shfl_xor(s, m, 64);
    s2 += __shfl_xor(s2, m, 64);
  }
  const float mean = s * (1.f / 512.f);
  const float var = s2 * (1.f / 512.f) - mean * mean;
  const float rstd = rsqrtf(var + 1e-5f);
  const int c = lane * 8;
  u16x8 ov;
#pragma unroll
  for (int i = 0; i < 8; ++i) ov[i] = f2bf((v[i] - mean) * rstd * g[c + i] + b[c + i]);
  *(u16x8*)(out + base) = ov;
}

// ---------------------------------------------------------------------------
// Weight transpose fp32 (Kin x Nin) -> bf16 (Nout x Kout), zero-padded.
// ---------------------------------------------------------------------------
__global__ __launch_bounds__(256) void transpose_w(const float* __restrict__ in,
                                                   unsigned short* __restrict__ out,
                                                   int Kin, int Nin, int Kout, int Nout) {
  __shared__ float tile[32][33];
  const int nb = blockIdx.x * 32, kb = blockIdx.y * 32;
  const int tx = threadIdx.x & 31, ty = threadIdx.x >> 5;
#pragma unroll
  for (int i = 0; i < 32; i += 8) {
    int k = kb + ty + i, n = nb + tx;
    tile[ty + i][tx] = (k < Kin && n < Nin) ? in[(size_t)k * Nin + n] : 0.f;
  }
  __syncthreads();
#pragma unroll
  for (int i = 0; i < 32; i += 8) {
    int n = nb + ty + i, k = kb + tx;
    if (n < Nout && k < Kout) out[(size_t)n * Kout + k] = f2bf(tile[tx][ty + i]);
  }
}

// x (64 x 20480) fp32 -> xpad (65536 tok x 64) bf16 (K padded 20->64)
__global__ __launch_bounds__(256) void xpad_k(const float* __restrict__ x,
                                              unsigned short* __restrict__ xp) {
  const int idx = blockIdx.x * 256 + threadIdx.x;  // 65536*64
  const int tok = idx >> 6, k = idx & 63;
  const int seq = tok >> 9, s = tok & 511;
  const int hf = seq >> 6, b = seq & 63;
  float v = 0.f;
  if (k < 20) v = x[(size_t)b * 20480 + hf * 10240 + s * 20 + k];
  xp[idx] = f2bf(v);
}

// ---------------------------------------------------------------------------
// Head d1: h(64 x 32768) @ d1_W(32768 x 256). 256 K-slices of 128; W read once.
// ---------------------------------------------------------------------------
__global__ __launch_bounds__(256) void d1_part(const unsigned short* __restrict__ enc,
                                               const float* __restrict__ W,
                                               float* __restrict__ pz) {
  __shared__ float ef[64 * 128];  // 32 KB
  const int tid = threadIdx.x;
  const int kb = blockIdx.x * 128;
  const int hf = kb >> 14;
  const int j0 = kb & 16383;
  {
    const int m = tid >> 2, c = (tid & 3) * 32;
    const unsigned short* src = enc + (size_t)hf * 1048576 + (size_t)m * 16384 + j0 + c;
#pragma unroll
    for (int i = 0; i < 4; ++i) {
      u16x8 v = *(const u16x8*)(src + i * 8);
#pragma unroll
      for (int jj = 0; jj < 8; ++jj) ef[m * 128 + c + i * 8 + jj] = bf2f(v[jj]);
    }
  }
  __syncthreads();
  const int n = tid;
  float acc[64];
#pragma unroll
  for (int m = 0; m < 64; ++m) acc[m] = 0.f;
  for (int kc = 0; kc < 128; kc += 4) {
    const float w0 = W[(size_t)(kb + kc) * 256 + n];
    const float w1 = W[(size_t)(kb + kc + 1) * 256 + n];
    const float w2 = W[(size_t)(kb + kc + 2) * 256 + n];
    const float w3 = W[(size_t)(kb + kc + 3) * 256 + n];
#pragma unroll
    for (int m = 0; m < 64; ++m) {
      const f32x4 e = *(const f32x4*)(ef + m * 128 + kc);
      acc[m] += e[0] * w0 + e[1] * w1 + e[2] * w2 + e[3] * w3;
    }
  }
#pragma unroll
  for (int m = 0; m < 64; ++m)
    pz[(size_t)(blockIdx.x * 64 + m) * 256 + n] = acc[m];
}

__global__ __launch_bounds__(256) void d1_fin(const float* __restrict__ pz,
                                              const float* __restrict__ d1b,
                                              const float* __restrict__ g,
                                              const float* __restrict__ b,
                                              const float* __restrict__ mm,
                                              const float* __restrict__ vv,
                                              float* __restrict__ h1) {
  const int m = blockIdx.x, n = threadIdx.x;
  float a = d1b[n];
  for (int sl = 0; sl < 256; ++sl) a += pz[(size_t)(sl * 64 + m) * 256 + n];
  a = fmaxf(a, 0.f);
  a = (a - mm[n]) * rsqrtf(vv[n] + 1e-5f) * g[n] + b[n];
  h1[m * 256 + n] = a;
}

__global__ __launch_bounds__(128) void d2_k(const float* __restrict__ h1,
                                            const float* __restrict__ W,
                                            const float* __restrict__ bb,
                                            const float* __restrict__ g,
                                            const float* __restrict__ b,
                                            const float* __restrict__ mm,
                                            const float* __restrict__ vv,
                                            float* __restrict__ h2) {
  __shared__ float hs[256];
  const int m = blockIdx.x, n = threadIdx.x;
  hs[n] = h1[m * 256 + n];
  hs[n + 128] = h1[m * 256 + n + 128];
  __syncthreads();
  float a = bb[n];
#pragma unroll 8
  for (int k = 0; k < 256; ++k) a += hs[k] * W[k * 128 + n];
  a = fmaxf(a, 0.f);
  a = (a - mm[n]) * rsqrtf(vv[n] + 1e-5f) * g[n] + b[n];
  h2[m * 128 + n] = a;
}

__global__ __launch_bounds__(64) void fin_k(const float* __restrict__ h2,
                                            const float* __restrict__ W,
                                            const float* __restrict__ fb,
                                            float* __restrict__ out) {
  const int m = threadIdx.x;
  float a = fb[0];
#pragma unroll 8
  for (int k = 0; k < 128; ++k) a += h2[m * 128 + k] * W[k];
  out[m] = a;
}

// ---------------------------------------------------------------------------
extern "C" void kernel_launch(void* const* d_in, const int* in_sizes, int n_in,
                              void* d_out, int out_size, void* d_ws, size_t ws_size,
                              hipStream_t stream) {
  const float* x      = (const float*)d_in[0];
  const float* in_W   = (const float*)d_in[1];
  const float* in_b   = (const float*)d_in[2];
  const float* qkv_W  = (const float*)d_in[3];
  const float* qkv_b  = (const float*)d_in[4];
  const float* ln1_g  = (const float*)d_in[5];
  const float* ln1_b  = (const float*)d_in[6];
  const float* ffn_W1 = (const float*)d_in[7];
  const float* ffn_b1 = (const float*)d_in[8];
  const float* ffn_W2 = (const float*)d_in[9];
  const float* ffn_b2 = (const float*)d_in[10];
  const float* ln2_g  = (const float*)d_in[11];
  const float* ln2_b  = (const float*)d_in[12];
  const float* out_W  = (const float*)d_in[13];
  const float* out_b  = (const float*)d_in[14];
  const float* d1W    = (const float*)d_in[15];
  const float* d1b    = (const float*)d_in[16];
  const float* bn1g   = (const float*)d_in[17];
  const float* bn1b   = (const float*)d_in[18];
  const float* bn1m   = (const float*)d_in[19];
  const float* bn1v   = (const float*)d_in[20];
  const float* d2W    = (const float*)d_in[21];
  const float* d2b    = (const float*)d_in[22];
  const float* bn2g   = (const float*)d_in[23];
  const float* bn2b   = (const float*)d_in[24];
  const float* bn2m   = (const float*)d_in[25];
  const float* bn2v   = (const float*)d_in[26];
  const float* finW   = (const float*)d_in[27];
  const float* finb   = (const float*)d_in[28];
  (void)in_sizes; (void)n_in; (void)out_size; (void)ws_size;

  char* ws = (char*)d_ws;
  size_t off = 0;
  auto alloc = [&](size_t bytes) {
    char* p = ws + off;
    off += (bytes + 255) & ~(size_t)255;
    return p;
  };
  unsigned short* t     = (unsigned short*)alloc(32768ull * 512 * 2);   //  33.5 MB
  unsigned short* big   = (unsigned short*)alloc(32768ull * 2048 * 2);  // 134 MB (qkv+vt / f1 / pz)
  unsigned short* ob    = (unsigned short*)alloc(32768ull * 512 * 2);   //  33.5 MB (o / y)
  unsigned short* xpad  = (unsigned short*)alloc(65536ull * 64 * 2);    //   8.4 MB
  unsigned short* enc   = (unsigned short*)alloc(65536ull * 32 * 2);
  unsigned short* inWt  = (unsigned short*)alloc(512ull * 64 * 2);
  unsigned short* qkvWt = (unsigned short*)alloc(4ull * 1536 * 512 * 2);
  unsigned short* f1Wt  = (unsigned short*)alloc(4ull * 2048 * 512 * 2);
  unsigned short* f2Wt  = (unsigned short*)alloc(4ull * 512 * 2048 * 2);
  unsigned short* outWt = (unsigned short*)alloc(128ull * 512 * 2);
  float* h1 = (float*)alloc(64ull * 256 * 4);
  float* h2 = (float*)alloc(64ull * 128 * 4);
  float* pz = (float*)big;                               // big free by d1 time
  unsigned short* vtb = big + (size_t)32768 * 1536;      // upper 33.5 MB of big

  xpad_k<<<16384, 256, 0, stream>>>(x, xpad);
  transpose_w<<<dim3(16, 2), 256, 0, stream>>>(in_W, inWt, 20, 512, 64, 512);
  transpose_w<<<dim3(4, 16), 256, 0, stream>>>(out_W, outWt, 512, 32, 512, 128);
  for (int l = 0; l < 4; ++l) {
    transpose_w<<<dim3(48, 16), 256, 0, stream>>>(qkv_W + (size_t)l * 512 * 1536,
                                                  qkvWt + (size_t)l * 1536 * 512, 512, 1536, 512, 1536);
    transpose_w<<<dim3(64, 16), 256, 0, stream>>>(ffn_W1 + (size_t)l * 512 * 2048,
                                                  f1Wt + (size_t)l * 2048 * 512, 512, 2048, 512, 2048);
    transpose_w<<<dim3(16, 64), 256, 0, stream>>>(ffn_W2 + (size_t)l * 2048 * 512,
                                                  f2Wt + (size_t)l * 512 * 2048, 2048, 512, 2048, 512);
  }

  for (int hf = 0; hf < 2; ++hf) {
    gemm32_k<EPI_BIAS><<<dim3(2, 128), 512, 0, stream>>>(xpad + (size_t)hf * 32768 * 64, inWt, in_b, t, nullptr, 512, 64);
    for (int l = 0; l < 4; ++l) {
      gemm32_k<EPI_QKV><<<dim3(6, 128), 512, 0, stream>>>(t, qkvWt + (size_t)l * 1536 * 512,
                                                          qkv_b + l * 1536, big, vtb, 1536, 512);
      attn_k<<<dim3(512, 4), 256, 0, stream>>>(big, vtb, ob);
      ln_k<<<8192, 256, 0, stream>>>(t, ob, ln1_g + l * 512, ln1_b + l * 512, t);
      gemm32_k<EPI_RELU><<<dim3(8, 128), 512, 0, stream>>>(t, f1Wt + (size_t)l * 2048 * 512,
                                                           ffn_b1 + l * 2048, big, nullptr, 2048, 512);
      gemm32_k<EPI_BIAS><<<dim3(2, 128), 512, 0, stream>>>(big, f2Wt + (size_t)l * 512 * 2048,
                                                           ffn_b2 + l * 512, ob, nullptr, 512, 2048);
      ln_k<<<8192, 256, 0, stream>>>(t, ob, ln2_g + l * 512, ln2_b + l * 512, t);
    }
    gemm_k<EPI_OUT><<<dim3(1, 256), 256, 0, stream>>>(t, outWt, out_b,
                                                      enc + (size_t)hf * 32768 * 32, 128, 512);
  }

  d1_part<<<256, 256, 0, stream>>>(enc, d1W, pz);
  d1_fin<<<64, 256, 0, stream>>>(pz, d1b, bn1g, bn1b, bn1m, bn1v, h1);
  d2_k<<<64, 128, 0, stream>>>(h1, d2W, d2b, bn2g, bn2b, bn2m, bn2v, h2);
  fin_k<<<1, 64, 0, stream>>>(h2, finW, finb, (float*)d_out);
}

// Round 9
// 2933.180 us; speedup vs baseline: 1.0988x; 1.0988x over previous
//
#include <hip/hip_runtime.h>

#define DEV __device__ __forceinline__

using bf16x8 = __attribute__((ext_vector_type(8))) __bf16;
using f32x4  = __attribute__((ext_vector_type(4))) float;
using u16x8  = __attribute__((ext_vector_type(8))) unsigned short;
using u16x4  = __attribute__((ext_vector_type(4))) unsigned short;

DEV unsigned short f2bf(float f) {
  unsigned u = __builtin_bit_cast(unsigned, f);
  u += 0x7fffu + ((u >> 16) & 1u);
  return (unsigned short)(u >> 16);
}
DEV float bf2f(unsigned short h) {
  unsigned u = ((unsigned)h) << 16;
  return __builtin_bit_cast(float, u);
}
DEV f32x4 mfma16(u16x8 a, u16x8 b, f32x4 c) {
  return __builtin_amdgcn_mfma_f32_16x16x32_bf16(
      __builtin_bit_cast(bf16x8, a), __builtin_bit_cast(bf16x8, b), c, 0, 0, 0);
}
DEV f32x4 zero4() { f32x4 z = {0.f, 0.f, 0.f, 0.f}; return z; }

// async global->LDS, 16B per lane. lds dest = wave-uniform base + lane*16;
// global src is per-lane.
DEV void glds16(const unsigned short* g, unsigned short* l) {
  __builtin_amdgcn_global_load_lds(
      (const __attribute__((address_space(1))) unsigned int*)g,
      (__attribute__((address_space(3))) unsigned int*)l, 16, 0, 0);
}

#define PH_BAR()                          \
  do {                                    \
    __builtin_amdgcn_sched_barrier(0);    \
    __builtin_amdgcn_s_barrier();         \
    __builtin_amdgcn_sched_barrier(0);    \
  } while (0)

enum { EPI_BIAS = 0, EPI_RELU = 1, EPI_QKV = 3 };

// ---------------------------------------------------------------------------
// 8-phase 256x256 bf16 MFMA GEMM (best-measured structure, R5/R7: 93 us ffn1).
// BK=64/tile, 4 phases/tile, 512 thr = 8 waves (2M x 4N), per-wave 128x64,
// acc[8][4]. LDS 128 KB (2buf x A/B 256x64). Counted vmcnt(4) once per tile.
// Swizzle: chunk c of row r at slot c^(r&7) (measured 0-conflict).
// EPI_QKV: n0>=1024 tiles (V block) written TRANSPOSED into Cv (vt layout);
// 4 consecutive rows = 4 keys = one 8B store. Bit-identical values.
// Requires M%256==0, N%256==0, K%64==0, Mt%8==0.
// ---------------------------------------------------------------------------
template <int EPI>
__global__ __launch_bounds__(512, 1) void gemm8p_k(
    const unsigned short* __restrict__ A, const unsigned short* __restrict__ Bt,
    const float* __restrict__ bias, unsigned short* __restrict__ C,
    unsigned short* __restrict__ Cv, int N, int K) {
  __shared__ unsigned short As[2][16384];  // [buf][256 rows x 64 shorts]
  __shared__ unsigned short Bs[2][16384];
  const int tid = threadIdx.x;
  const int lane = tid & 63, wv = tid >> 6;  // 8 waves
  const int q = lane >> 4, ln = lane & 15;
  const int wr = wv >> 2, wc = wv & 3;       // wave grid 2M x 4N
  const int ln7 = ln & 7;

  const int Nt = gridDim.x, Mt = gridDim.y;
  const int lin = blockIdx.x + Nt * blockIdx.y;
  const int xcd = lin & 7;
  const int j = lin >> 3;
  const int mi = xcd * (Mt >> 3) + j / Nt;
  const int ni = j % Nt;
  const int m0 = mi << 8, n0 = ni << 8;

  f32x4 acc[8][4];
#pragma unroll
  for (int i = 0; i < 8; ++i)
#pragma unroll
    for (int jj = 0; jj < 4; ++jj) acc[i][jj] = zero4();

  // staging: per glds a wave covers 8 rows x 64 cols (1 KB). lane L -> row
  // wv*8+(L>>3), dest chunk L&7; source chunk pre-swizzled (L&7)^(L>>3).
  const int sr = lane >> 3;
  const int sc = ((lane & 7) ^ sr) << 3;
  const unsigned short* Abase = A + (size_t)(m0 + wv * 8 + sr) * K + sc;
  const unsigned short* Bbase = Bt + (size_t)(n0 + wv * 8 + sr) * K + sc;

  const int T = K >> 6;  // 64-wide K-tiles

  auto stA = [&](int buf, int t, int half) {
    unsigned short* d = &As[buf][(half * 128 + wv * 8) * 64];
    const unsigned short* s = Abase + (size_t)(half * 128) * K + t * 64;
    glds16(s, d);
    glds16(s + (size_t)64 * K, d + 4096);
  };
  auto stB = [&](int buf, int t, int half) {
    unsigned short* d = &Bs[buf][(half * 128 + wv * 8) * 64];
    const unsigned short* s = Bbase + (size_t)(half * 128) * K + t * 64;
    glds16(s, d);
    glds16(s + (size_t)64 * K, d + 4096);
  };

  // prologue: t0 fully (B then A), then t1.B. vmcnt(4) -> t0 landed, t1.B in flight.
  stB(0, 0, 0);
  stB(0, 0, 1);
  stA(0, 0, 0);
  stA(0, 0, 1);
  if (T > 1) {
    stB(1, 1, 0);
    stB(1, 1, 1);
    asm volatile("s_waitcnt vmcnt(4)" ::: "memory");
  } else {
    asm volatile("s_waitcnt vmcnt(0)" ::: "memory");
  }
  PH_BAR();

  for (int u = 0; u < T; ++u) {
    const int cur = u & 1, nxt = cur ^ 1;
    const unsigned short* Ab = &As[cur][0];
    const unsigned short* Bb = &Bs[cur][0];
    u16x8 a0[4][2], a1[4][2], b0[2][2], b1[2][2];

    // ---- ph0: A0-3 + B0-1 (12 reads); stage (u+1).Alo
#pragma unroll
    for (int mt = 0; mt < 4; ++mt)
#pragma unroll
      for (int kk = 0; kk < 2; ++kk)
        a0[mt][kk] = *(const u16x8*)(Ab + (wr * 128 + mt * 16 + ln) * 64 +
                                     (((kk * 4 + q) ^ ln7) << 3));
#pragma unroll
    for (int nt = 0; nt < 2; ++nt)
#pragma unroll
      for (int kk = 0; kk < 2; ++kk)
        b0[nt][kk] = *(const u16x8*)(Bb + (wc * 64 + nt * 16 + ln) * 64 +
                                     (((kk * 4 + q) ^ ln7) << 3));
    if (u + 1 < T) stA(nxt, u + 1, 0);
    PH_BAR();
    __builtin_amdgcn_s_setprio(1);
#pragma unroll
    for (int kk = 0; kk < 2; ++kk)
#pragma unroll
      for (int nt = 0; nt < 2; ++nt)
#pragma unroll
        for (int mt = 0; mt < 4; ++mt)
          acc[mt][nt] = mfma16(a0[mt][kk], b0[nt][kk], acc[mt][nt]);
    __builtin_amdgcn_s_setprio(0);
    PH_BAR();

    // ---- ph1: B2-3 (4 reads); stage (u+1).Ahi
#pragma unroll
    for (int nt = 0; nt < 2; ++nt)
#pragma unroll
      for (int kk = 0; kk < 2; ++kk)
        b1[nt][kk] = *(const u16x8*)(Bb + (wc * 64 + (nt + 2) * 16 + ln) * 64 +
                                     (((kk * 4 + q) ^ ln7) << 3));
    if (u + 1 < T) stA(nxt, u + 1, 1);
    PH_BAR();
    __builtin_amdgcn_s_setprio(1);
#pragma unroll
    for (int kk = 0; kk < 2; ++kk)
#pragma unroll
      for (int nt = 0; nt < 2; ++nt)
#pragma unroll
        for (int mt = 0; mt < 4; ++mt)
          acc[mt][nt + 2] = mfma16(a0[mt][kk], b1[nt][kk], acc[mt][nt + 2]);
    __builtin_amdgcn_s_setprio(0);
    PH_BAR();

    // ---- ph2: A4-7 (8 reads); stage (u+2).Blo (same buf; B-reads ended ph1)
#pragma unroll
    for (int mt = 0; mt < 4; ++mt)
#pragma unroll
      for (int kk = 0; kk < 2; ++kk)
        a1[mt][kk] = *(const u16x8*)(Ab + (wr * 128 + (mt + 4) * 16 + ln) * 64 +
                                     (((kk * 4 + q) ^ ln7) << 3));
    if (u + 2 < T) stB(cur, u + 2, 0);
    PH_BAR();
    __builtin_amdgcn_s_setprio(1);
#pragma unroll
    for (int kk = 0; kk < 2; ++kk)
#pragma unroll
      for (int nt = 0; nt < 2; ++nt)
#pragma unroll
        for (int mt = 0; mt < 4; ++mt)
          acc[mt + 4][nt] = mfma16(a1[mt][kk], b0[nt][kk], acc[mt + 4][nt]);
    __builtin_amdgcn_s_setprio(0);
    PH_BAR();

    // ---- ph3: no reads; stage (u+2).Bhi; boundary vmcnt after MFMA
    if (u + 2 < T) stB(cur, u + 2, 1);
    PH_BAR();
    __builtin_amdgcn_s_setprio(1);
#pragma unroll
    for (int kk = 0; kk < 2; ++kk)
#pragma unroll
      for (int nt = 0; nt < 2; ++nt)
#pragma unroll
        for (int mt = 0; mt < 4; ++mt)
          acc[mt + 4][nt + 2] = mfma16(a1[mt][kk], b1[nt][kk], acc[mt + 4][nt + 2]);
    __builtin_amdgcn_s_setprio(0);
    if (u + 1 < T) {
      if (u + 2 < T) {
        asm volatile("s_waitcnt vmcnt(4)" ::: "memory");
      } else {
        asm volatile("s_waitcnt vmcnt(0)" ::: "memory");
      }
      PH_BAR();
    }
  }

#pragma unroll
  for (int mt = 0; mt < 8; ++mt) {
    const int rowb = m0 + wr * 128 + mt * 16 + q * 4;
    const int seq = rowb >> 9, key0 = rowb & 511;
#pragma unroll
    for (int nt = 0; nt < 4; ++nt) {
      const int col = n0 + wc * 64 + nt * 16 + ln;
      const float bs = bias[col];
      if (EPI == EPI_QKV && n0 >= 1024) {
        // V block: write transposed into vt [(seq*8+h)*64+hd][512 keys]
        const int hh = (col - 1024) >> 6, hd = col & 63;
        u16x4 pk;
#pragma unroll
        for (int r = 0; r < 4; ++r) pk[r] = f2bf(acc[mt][nt][r] + bs);
        *(u16x4*)(Cv + ((size_t)((seq * 8 + hh) * 64 + hd)) * 512 + key0) = pk;
      } else {
#pragma unroll
        for (int r = 0; r < 4; ++r) {
          float v = acc[mt][nt][r] + bs;
          if (EPI == EPI_RELU) v = fmaxf(v, 0.f);
          C[(size_t)(rowb + r) * N + col] = f2bf(v);
        }
      }
    }
  }
}

// ---------------------------------------------------------------------------
// Dedicated out-proj: C[32768 x 32] = A[32768 x 512] @ Wt[32 x 512]^T + bias.
// Replaces the old 128^2 gemm (which computed 128 cols, kept 32 -> 75% waste).
// grid 128 blocks (256 rows), 256 thr = 4 waves (64 rows each). B resident in
// LDS (stride 520 -> 2-way/free). A staged per K=32 tile via glds16 with the
// r8-verified 0-conflict swizzle pair (stage src (L&3)^((L>>3)&3), row L>>2;
// read (q ^ ((ln>>1)&3))). 49.7 KB LDS.
// ---------------------------------------------------------------------------
__global__ __launch_bounds__(256) void outp_k(
    const unsigned short* __restrict__ A, const unsigned short* __restrict__ Bt,
    const float* __restrict__ bias, unsigned short* __restrict__ C) {
  __shared__ unsigned short Asb[256 * 32];  // 16 KB
  __shared__ unsigned short Bsb[32 * 520];  // 33.3 KB
  const int tid = threadIdx.x;
  const int lane = tid & 63, wv = tid >> 6;  // 4 waves
  const int q = lane >> 4, ln = lane & 15;
  const int m0 = blockIdx.x << 8;
  const int sw = ((q ^ ((ln >> 1) & 3)) << 3);

  {  // load B once: 32 rows x 512 cols; thread t -> row t>>3, cols (t&7)*64
    const int br = tid >> 3, bc = (tid & 7) * 64;
    const unsigned short* src = Bt + (size_t)br * 512 + bc;
#pragma unroll
    for (int i = 0; i < 8; ++i)
      *(u16x8*)(Bsb + br * 520 + bc + i * 8) = *(const u16x8*)(src + i * 8);
  }

  f32x4 acc[4][2];
#pragma unroll
  for (int i = 0; i < 4; ++i)
#pragma unroll
    for (int jj = 0; jj < 2; ++jj) acc[i][jj] = zero4();

  // A staging: wave rows wv*64..+63; per glds event 16 rows x 32 cols (1 KB).
  const int sr = lane >> 2;
  const int sc = ((lane & 3) ^ ((lane >> 3) & 3)) << 3;
  const unsigned short* Ap = A + (size_t)(m0 + wv * 64 + sr) * 512 + sc;
  unsigned short* AsW = Asb + (wv * 64) * 32;

  for (int kb = 0; kb < 512; kb += 32) {
    __syncthreads();  // prior reads done before overwrite
    glds16(Ap + kb, AsW);
    glds16(Ap + (size_t)16 * 512 + kb, AsW + 512);
    glds16(Ap + (size_t)32 * 512 + kb, AsW + 1024);
    glds16(Ap + (size_t)48 * 512 + kb, AsW + 1536);
    __syncthreads();  // drains vmcnt -> tile visible
    u16x8 af[4];
#pragma unroll
    for (int mt = 0; mt < 4; ++mt)
      af[mt] = *(const u16x8*)(Asb + (wv * 64 + mt * 16 + ln) * 32 + sw);
#pragma unroll
    for (int nt = 0; nt < 2; ++nt) {
      u16x8 bf = *(const u16x8*)(Bsb + (nt * 16 + ln) * 520 + kb + q * 8);
#pragma unroll
      for (int mt = 0; mt < 4; ++mt) acc[mt][nt] = mfma16(af[mt], bf, acc[mt][nt]);
    }
  }

#pragma unroll
  for (int mt = 0; mt < 4; ++mt) {
    const int rowb = m0 + wv * 64 + mt * 16 + q * 4;
#pragma unroll
    for (int nt = 0; nt < 2; ++nt) {
      const int col = nt * 16 + ln;  // always < 32
      const float bs = bias[col];
#pragma unroll
      for (int r = 0; r < 4; ++r)
        C[(size_t)(rowb + r) * 32 + col] = f2bf(acc[mt][nt][r] + bs);
    }
  }
}

// ---------------------------------------------------------------------------
// Flash attention with alibi, NO max-subtraction (scores bounded; exp2 direct).
// Swapped QK^T; b64 P-stores; K/V DOUBLE-BUFFERED with counted vmcnt so the
// next tile's fetch hides under this tile's compute. Ps aliases Qs. 50 KB LDS.
// ---------------------------------------------------------------------------
__global__ __launch_bounds__(256) void attn_k(const unsigned short* __restrict__ qkv,
                                              const unsigned short* __restrict__ vt,
                                              unsigned short* __restrict__ o) {
  __shared__ unsigned short Qs[128 * 72];    // Q tile; reused as Ps after prologue
  __shared__ unsigned short Ks[2][64 * 64];  // XOR-chunk swizzled, glds16-staged
  __shared__ unsigned short Vts[2][64 * 64]; // [hd][key-chunk swizzled]
  unsigned short* Ps = Qs;
  const int tid = threadIdx.x;
  const int lane = tid & 63, w = tid >> 6, q = lane >> 4, ln = lane & 15;
  const int bh = blockIdx.x;
  const int seq = bh >> 3, h = bh & 7;
  const int qt = blockIdx.y;
  const size_t tokb = (size_t)seq * 512;
  const int qoff = h * 64, koff = 512 + h * 64;
  const float c1 = 0.125f * 1.44269504f;                   // scale * log2e
  const float c2 = ((h < 4) ? 1.0f : 0.5f) * 1.44269504f;  // slope * log2e

#pragma unroll
  for (int p = 0; p < 4; ++p) {  // stage Q 128x64 (stride 72)
    int c = p * 256 + tid;
    int row = c >> 3, cc = (c & 7) << 3;
    u16x8 v = *(const u16x8*)(qkv + (tokb + qt * 128 + row) * 1536 + qoff + cc);
    *(u16x8*)(Qs + row * 72 + cc) = v;
  }

  const int sr = lane >> 3;                // row-in-8
  const int sc = ((lane & 7) ^ sr) << 3;   // swizzled chunk (shorts)
  const unsigned short* Kp = qkv + (tokb + w * 16 + sr) * 1536 + koff + sc;
  const unsigned short* Vp = vt + ((size_t)bh * 64 + w * 16 + sr) * 512 + sc;
  const int ln7 = ln & 7;

  auto stage = [&](int kt, int buf) {
    unsigned short* KsW = &Ks[buf][w * 1024];
    unsigned short* VsW = &Vts[buf][w * 1024];
    glds16(Kp + (size_t)(kt * 64) * 1536, KsW);
    glds16(Kp + (size_t)(kt * 64 + 8) * 1536, KsW + 512);
    glds16(Vp + kt * 64, VsW);
    glds16(Vp + kt * 64 + (size_t)8 * 512, VsW + 512);
  };

  stage(0, 0);  // prologue: kt0 in flight during Q staging

  __syncthreads();  // Q visible
  u16x8 aq[2][2];
#pragma unroll
  for (int mt = 0; mt < 2; ++mt)
#pragma unroll
    for (int kc = 0; kc < 2; ++kc)
      aq[mt][kc] = *(const u16x8*)(Qs + (w * 32 + mt * 16 + ln) * 72 + kc * 32 + q * 8);

  float lacc[2] = {0.f, 0.f};
  f32x4 o_acc[2][4];
#pragma unroll
  for (int mt = 0; mt < 2; ++mt)
#pragma unroll
    for (int ht = 0; ht < 4; ++ht) o_acc[mt][ht] = zero4();

  for (int kt = 0; kt < 8; ++kt) {
    const int buf = kt & 1;
    __syncthreads();  // all waves done with buf^1 (and Ps writes of kt-1 settled)
    if (kt + 1 < 8) {
      stage(kt + 1, buf ^ 1);
      asm volatile("s_waitcnt vmcnt(4)" ::: "memory");  // drain kt; kt+1 in flight
    } else {
      asm volatile("s_waitcnt vmcnt(0)" ::: "memory");
    }
    __builtin_amdgcn_sched_barrier(0);
    __builtin_amdgcn_s_barrier();  // kt's K/V visible to all waves
    __builtin_amdgcn_sched_barrier(0);

    // QK^T, SWAPPED operands: lane (q,ln) gets S[qrow=w*32+mt*16+ln][k=nt*16+q*4+r]
    f32x4 sacc[2][4];
#pragma unroll
    for (int mt = 0; mt < 2; ++mt)
#pragma unroll
      for (int nt = 0; nt < 4; ++nt) sacc[mt][nt] = zero4();
#pragma unroll
    for (int nt = 0; nt < 4; ++nt)
#pragma unroll
      for (int kc = 0; kc < 2; ++kc) {
        u16x8 bk = *(const u16x8*)(&Ks[buf][(nt * 16 + ln) * 64 + (((kc * 4 + q) ^ ln7) << 3)]);
#pragma unroll
        for (int mt = 0; mt < 2; ++mt) sacc[mt][nt] = mfma16(bk, aq[mt][kc], sacc[mt][nt]);
      }

    // P = exp2(S*c1 - c2*|dq-dk|); 4 contiguous k per (mt,nt) -> b64 stores.
    const float qp0 = (float)(qt * 128 + w * 32 + ln);
    const float kb0 = (float)(kt * 64 + q * 4);
#pragma unroll
    for (int mt = 0; mt < 2; ++mt) {
      const float qpm = qp0 + (float)(mt * 16);
#pragma unroll
      for (int nt = 0; nt < 4; ++nt) {
        const float kp = kb0 + (float)(nt * 16);
        u16x4 pk;
#pragma unroll
        for (int r = 0; r < 4; ++r) {
          const float ad = fabsf(qpm - (kp + (float)r));
          const float p = exp2f(fmaf(sacc[mt][nt][r], c1, -c2 * ad));
          const unsigned u = __builtin_bit_cast(unsigned, p);
          const unsigned short pb = (unsigned short)((u + 0x8000u) >> 16);
          pk[r] = pb;
          lacc[mt] += bf2f(pb);  // sum of the *stored* values
        }
        *(u16x4*)(Ps + (w * 32 + mt * 16 + ln) * 72 + nt * 16 + q * 4) = pk;
      }
    }
    // P @ V  (Ps rows are wave-private; in-wave LDS ordering suffices)
#pragma unroll
    for (int kc = 0; kc < 2; ++kc) {
      u16x8 pa[2];
#pragma unroll
      for (int mt = 0; mt < 2; ++mt)
        pa[mt] = *(const u16x8*)(Ps + (w * 32 + mt * 16 + ln) * 72 + kc * 32 + q * 8);
#pragma unroll
      for (int ht = 0; ht < 4; ++ht) {
        u16x8 bv = *(const u16x8*)(&Vts[buf][(ht * 16 + ln) * 64 + (((kc * 4 + q) ^ ln7) << 3)]);
#pragma unroll
        for (int mt = 0; mt < 2; ++mt) o_acc[mt][ht] = mfma16(pa[mt], bv, o_acc[mt][ht]);
      }
    }
  }

  // row-sums: reduce across q-groups, redistribute to o_acc layout via shfl.
  float rl[2][4];
#pragma unroll
  for (int mt = 0; mt < 2; ++mt) {
    float l = lacc[mt];
    l += __shfl_xor(l, 16, 64);
    l += __shfl_xor(l, 32, 64);
    const int sb = (lane >> 4) * 20;
#pragma unroll
    for (int r = 0; r < 4; ++r) rl[mt][r] = 1.0f / __shfl(l, sb + r, 64);
  }

#pragma unroll
  for (int mt = 0; mt < 2; ++mt)
#pragma unroll
    for (int ht = 0; ht < 4; ++ht)
#pragma unroll
      for (int r = 0; r < 4; ++r) {
        const int row = qt * 128 + w * 32 + mt * 16 + q * 4 + r;
        const float val = o_acc[mt][ht][r] * rl[mt][r];
        o[(tokb + row) * 512 + h * 64 + ht * 16 + ln] = f2bf(val);
      }
}

// ---------------------------------------------------------------------------
// Fused residual + LayerNorm (in-place capable)
// ---------------------------------------------------------------------------
__global__ __launch_bounds__(256) void ln_k(const unsigned short* res,
                                            const unsigned short* __restrict__ y,
                                            const float* __restrict__ g,
                                            const float* __restrict__ b,
                                            unsigned short* out) {
  const int lane = threadIdx.x & 63, wv = threadIdx.x >> 6;
  const size_t row = (size_t)blockIdx.x * 4 + wv;
  const size_t base = row * 512 + lane * 8;
  u16x8 rv = *(const u16x8*)(res + base);
  u16x8 yv = *(const u16x8*)(y + base);
  float v[8];
  float s = 0.f, s2 = 0.f;
#pragma unroll
  for (int i = 0; i < 8; ++i) {
    v[i] = bf2f(rv[i]) + bf2f(yv[i]);
    s += v[i];
    s2 += v[i] * v[i];
  }
#pragma unroll
  for (int m = 1; m < 64; m <<= 1) {
    s += __shfl_xor(s, m, 64);
    s2 += __shfl_xor(s2, m, 64);
  }
  const float mean = s * (1.f / 512.f);
  const float var = s2 * (1.f / 512.f) - mean * mean;
  const float rstd = rsqrtf(var + 1e-5f);
  const int c = lane * 8;
  u16x8 ov;
#pragma unroll
  for (int i = 0; i < 8; ++i) ov[i] = f2bf((v[i] - mean) * rstd * g[c + i] + b[c + i]);
  *(u16x8*)(out + base) = ov;
}

// ---------------------------------------------------------------------------
// Weight transpose fp32 (Kin x Nin) -> bf16 (Nout x Kout), zero-padded.
// ---------------------------------------------------------------------------
__global__ __launch_bounds__(256) void transpose_w(const float* __restrict__ in,
                                                   unsigned short* __restrict__ out,
                                                   int Kin, int Nin, int Kout, int Nout) {
  __shared__ float tile[32][33];
  const int nb = blockIdx.x * 32, kb = blockIdx.y * 32;
  const int tx = threadIdx.x & 31, ty = threadIdx.x >> 5;
#pragma unroll
  for (int i = 0; i < 32; i += 8) {
    int k = kb + ty + i, n = nb + tx;
    tile[ty + i][tx] = (k < Kin && n < Nin) ? in[(size_t)k * Nin + n] : 0.f;
  }
  __syncthreads();
#pragma unroll
  for (int i = 0; i < 32; i += 8) {
    int n = nb + ty + i, k = kb + tx;
    if (n < Nout && k < Kout) out[(size_t)n * Kout + k] = f2bf(tile[tx][ty + i]);
  }
}

// x (64 x 20480) fp32 -> xpad (65536 tok x 64) bf16 (K padded 20->64)
__global__ __launch_bounds__(256) void xpad_k(const float* __restrict__ x,
                                              unsigned short* __restrict__ xp) {
  const int idx = blockIdx.x * 256 + threadIdx.x;  // 65536*64
  const int tok = idx >> 6, k = idx & 63;
  const int seq = tok >> 9, s = tok & 511;
  const int hf = seq >> 6, b = seq & 63;
  float v = 0.f;
  if (k < 20) v = x[(size_t)b * 20480 + hf * 10240 + s * 20 + k];
  xp[idx] = f2bf(v);
}

// ---------------------------------------------------------------------------
// Head d1: h(64 x 32768) @ d1_W(32768 x 256). 256 K-slices of 128; W read once.
// ---------------------------------------------------------------------------
__global__ __launch_bounds__(256) void d1_part(const unsigned short* __restrict__ enc,
                                               const float* __restrict__ W,
                                               float* __restrict__ pz) {
  __shared__ float ef[64 * 128];  // 32 KB
  const int tid = threadIdx.x;
  const int kb = blockIdx.x * 128;
  const int hf = kb >> 14;
  const int j0 = kb & 16383;
  {
    const int m = tid >> 2, c = (tid & 3) * 32;
    const unsigned short* src = enc + (size_t)hf * 1048576 + (size_t)m * 16384 + j0 + c;
#pragma unroll
    for (int i = 0; i < 4; ++i) {
      u16x8 v = *(const u16x8*)(src + i * 8);
#pragma unroll
      for (int jj = 0; jj < 8; ++jj) ef[m * 128 + c + i * 8 + jj] = bf2f(v[jj]);
    }
  }
  __syncthreads();
  const int n = tid;
  float acc[64];
#pragma unroll
  for (int m = 0; m < 64; ++m) acc[m] = 0.f;
  for (int kc = 0; kc < 128; kc += 4) {
    const float w0 = W[(size_t)(kb + kc) * 256 + n];
    const float w1 = W[(size_t)(kb + kc + 1) * 256 + n];
    const float w2 = W[(size_t)(kb + kc + 2) * 256 + n];
    const float w3 = W[(size_t)(kb + kc + 3) * 256 + n];
#pragma unroll
    for (int m = 0; m < 64; ++m) {
      const f32x4 e = *(const f32x4*)(ef + m * 128 + kc);
      acc[m] += e[0] * w0 + e[1] * w1 + e[2] * w2 + e[3] * w3;
    }
  }
#pragma unroll
  for (int m = 0; m < 64; ++m)
    pz[(size_t)(blockIdx.x * 64 + m) * 256 + n] = acc[m];
}

__global__ __launch_bounds__(256) void d1_fin(const float* __restrict__ pz,
                                              const float* __restrict__ d1b,
                                              const float* __restrict__ g,
                                              const float* __restrict__ b,
                                              const float* __restrict__ mm,
                                              const float* __restrict__ vv,
                                              float* __restrict__ h1) {
  const int m = blockIdx.x, n = threadIdx.x;
  float a = d1b[n];
  for (int sl = 0; sl < 256; ++sl) a += pz[(size_t)(sl * 64 + m) * 256 + n];
  a = fmaxf(a, 0.f);
  a = (a - mm[n]) * rsqrtf(vv[n] + 1e-5f) * g[n] + b[n];
  h1[m * 256 + n] = a;
}

__global__ __launch_bounds__(128) void d2_k(const float* __restrict__ h1,
                                            const float* __restrict__ W,
                                            const float* __restrict__ bb,
                                            const float* __restrict__ g,
                                            const float* __restrict__ b,
                                            const float* __restrict__ mm,
                                            const float* __restrict__ vv,
                                            float* __restrict__ h2) {
  __shared__ float hs[256];
  const int m = blockIdx.x, n = threadIdx.x;
  hs[n] = h1[m * 256 + n];
  hs[n + 128] = h1[m * 256 + n + 128];
  __syncthreads();
  float a = bb[n];
#pragma unroll 8
  for (int k = 0; k < 256; ++k) a += hs[k] * W[k * 128 + n];
  a = fmaxf(a, 0.f);
  a = (a - mm[n]) * rsqrtf(vv[n] + 1e-5f) * g[n] + b[n];
  h2[m * 128 + n] = a;
}

__global__ __launch_bounds__(64) void fin_k(const float* __restrict__ h2,
                                            const float* __restrict__ W,
                                            const float* __restrict__ fb,
                                            float* __restrict__ out) {
  const int m = threadIdx.x;
  float a = fb[0];
#pragma unroll 8
  for (int k = 0; k < 128; ++k) a += h2[m * 128 + k] * W[k];
  out[m] = a;
}

// ---------------------------------------------------------------------------
extern "C" void kernel_launch(void* const* d_in, const int* in_sizes, int n_in,
                              void* d_out, int out_size, void* d_ws, size_t ws_size,
                              hipStream_t stream) {
  const float* x      = (const float*)d_in[0];
  const float* in_W   = (const float*)d_in[1];
  const float* in_b   = (const float*)d_in[2];
  const float* qkv_W  = (const float*)d_in[3];
  const float* qkv_b  = (const float*)d_in[4];
  const float* ln1_g  = (const float*)d_in[5];
  const float* ln1_b  = (const float*)d_in[6];
  const float* ffn_W1 = (const float*)d_in[7];
  const float* ffn_b1 = (const float*)d_in[8];
  const float* ffn_W2 = (const float*)d_in[9];
  const float* ffn_b2 = (const float*)d_in[10];
  const float* ln2_g  = (const float*)d_in[11];
  const float* ln2_b  = (const float*)d_in[12];
  const float* out_W  = (const float*)d_in[13];
  const float* out_b  = (const float*)d_in[14];
  const float* d1W    = (const float*)d_in[15];
  const float* d1b    = (const float*)d_in[16];
  const float* bn1g   = (const float*)d_in[17];
  const float* bn1b   = (const float*)d_in[18];
  const float* bn1m   = (const float*)d_in[19];
  const float* bn1v   = (const float*)d_in[20];
  const float* d2W    = (const float*)d_in[21];
  const float* d2b    = (const float*)d_in[22];
  const float* bn2g   = (const float*)d_in[23];
  const float* bn2b   = (const float*)d_in[24];
  const float* bn2m   = (const float*)d_in[25];
  const float* bn2v   = (const float*)d_in[26];
  const float* finW   = (const float*)d_in[27];
  const float* finb   = (const float*)d_in[28];
  (void)in_sizes; (void)n_in; (void)out_size; (void)ws_size;

  char* ws = (char*)d_ws;
  size_t off = 0;
  auto alloc = [&](size_t bytes) {
    char* p = ws + off;
    off += (bytes + 255) & ~(size_t)255;
    return p;
  };
  unsigned short* t     = (unsigned short*)alloc(32768ull * 512 * 2);   //  33.5 MB
  unsigned short* big   = (unsigned short*)alloc(32768ull * 2048 * 2);  // 134 MB (qkv+vt / f1 / pz)
  unsigned short* ob    = (unsigned short*)alloc(32768ull * 512 * 2);   //  33.5 MB (o / y)
  unsigned short* xpad  = (unsigned short*)alloc(65536ull * 64 * 2);    //   8.4 MB
  unsigned short* enc   = (unsigned short*)alloc(65536ull * 32 * 2);
  unsigned short* inWt  = (unsigned short*)alloc(512ull * 64 * 2);
  unsigned short* qkvWt = (unsigned short*)alloc(4ull * 1536 * 512 * 2);
  unsigned short* f1Wt  = (unsigned short*)alloc(4ull * 2048 * 512 * 2);
  unsigned short* f2Wt  = (unsigned short*)alloc(4ull * 512 * 2048 * 2);
  unsigned short* outWt = (unsigned short*)alloc(128ull * 512 * 2);
  float* h1 = (float*)alloc(64ull * 256 * 4);
  float* h2 = (float*)alloc(64ull * 128 * 4);
  float* pz = (float*)big;                               // big free by d1 time
  unsigned short* vtb = big + (size_t)32768 * 1536;      // upper 33.5 MB of big

  xpad_k<<<16384, 256, 0, stream>>>(x, xpad);
  transpose_w<<<dim3(16, 2), 256, 0, stream>>>(in_W, inWt, 20, 512, 64, 512);
  transpose_w<<<dim3(4, 16), 256, 0, stream>>>(out_W, outWt, 512, 32, 512, 128);
  for (int l = 0; l < 4; ++l) {
    transpose_w<<<dim3(48, 16), 256, 0, stream>>>(qkv_W + (size_t)l * 512 * 1536,
                                                  qkvWt + (size_t)l * 1536 * 512, 512, 1536, 512, 1536);
    transpose_w<<<dim3(64, 16), 256, 0, stream>>>(ffn_W1 + (size_t)l * 512 * 2048,
                                                  f1Wt + (size_t)l * 2048 * 512, 512, 2048, 512, 2048);
    transpose_w<<<dim3(16, 64), 256, 0, stream>>>(ffn_W2 + (size_t)l * 2048 * 512,
                                                  f2Wt + (size_t)l * 512 * 2048, 2048, 512, 2048, 512);
  }

  for (int hf = 0; hf < 2; ++hf) {
    gemm8p_k<EPI_BIAS><<<dim3(2, 128), 512, 0, stream>>>(xpad + (size_t)hf * 32768 * 64, inWt, in_b, t, nullptr, 512, 64);
    for (int l = 0; l < 4; ++l) {
      gemm8p_k<EPI_QKV><<<dim3(6, 128), 512, 0, stream>>>(t, qkvWt + (size_t)l * 1536 * 512,
                                                          qkv_b + l * 1536, big, vtb, 1536, 512);
      attn_k<<<dim3(512, 4), 256, 0, stream>>>(big, vtb, ob);
      ln_k<<<8192, 256, 0, stream>>>(t, ob, ln1_g + l * 512, ln1_b + l * 512, t);
      gemm8p_k<EPI_RELU><<<dim3(8, 128), 512, 0, stream>>>(t, f1Wt + (size_t)l * 2048 * 512,
                                                           ffn_b1 + l * 2048, big, nullptr, 2048, 512);
      gemm8p_k<EPI_BIAS><<<dim3(2, 128), 512, 0, stream>>>(big, f2Wt + (size_t)l * 512 * 2048,
                                                           ffn_b2 + l * 512, ob, nullptr, 512, 2048);
      ln_k<<<8192, 256, 0, stream>>>(t, ob, ln2_g + l * 512, ln2_b + l * 512, t);
    }
    outp_k<<<128, 256, 0, stream>>>(t, outWt, out_b, enc + (size_t)hf * 32768 * 32);
  }

  d1_part<<<256, 256, 0, stream>>>(enc, d1W, pz);
  d1_fin<<<64, 256, 0, stream>>>(pz, d1b, bn1g, bn1b, bn1m, bn1v, h1);
  d2_k<<<64, 128, 0, stream>>>(h1, d2W, d2b, bn2g, bn2b, bn2m, bn2v, h2);
  fin_k<<<1, 64, 0, stream>>>(h2, finW, finb, (float*)d_out);
}